// Round 1
// baseline (304.203 us; speedup 1.0000x reference)
//
#include <hip/hip_runtime.h>

constexpr int HH = 100;
constexpr int WW = 100;
constexpr int D  = 256;
constexpr int NH = 8;
constexpr int NP = 4;
constexpr int B  = 4;
constexpr int Q  = HH * WW;   // 10000
constexpr int S  = Q;
constexpr int K  = 256;
constexpr int DH = 32;        // head dim

// ---------------------------------------------------------------------------
// Tiled f32 GEMM: C = A[M,K] @ W[N,K]^T + bias[N]
// MODE 0: C[m*ldc + col_off + n]   (row-major with stride/offset)
// MODE 1: value layout: C[((b*NH+h)*S + s)*DH + dd], b=m/S, s=m%S, h=n>>5, dd=n&31
// Block: 256 threads, tile 64x64, BK=32, 4x4 accumulators per thread.
// ---------------------------------------------------------------------------
template <int MODE>
__global__ __launch_bounds__(256) void gemm_nt(
    const float* __restrict__ A, const float* __restrict__ Wt,
    const float* __restrict__ bias, float* __restrict__ C,
    int M, int N, int ldc, int col_off)
{
    __shared__ float As[32][68];   // [k][m], +4 pad keeps 16B alignment
    __shared__ float Ws[32][68];   // [k][n]

    const int tid = threadIdx.x;
    const int tx = tid & 15;       // col group
    const int ty = tid >> 4;       // row group
    const int m0 = blockIdx.y * 64;
    const int n0 = blockIdx.x * 64;

    const int lrow = tid >> 3;         // 0..31
    const int lk4  = (tid & 7) * 4;    // 0..28 step 4

    float acc[4][4] = {};

    for (int k0 = 0; k0 < K; k0 += 32) {
#pragma unroll
        for (int half = 0; half < 2; ++half) {
            const int r = lrow + half * 32;   // tile row 0..63
            float4 a = *reinterpret_cast<const float4*>(
                &A[(size_t)(m0 + r) * K + k0 + lk4]);
            As[lk4 + 0][r] = a.x;
            As[lk4 + 1][r] = a.y;
            As[lk4 + 2][r] = a.z;
            As[lk4 + 3][r] = a.w;
            const int n = n0 + r;
            float4 w;
            if (n < N) {
                w = *reinterpret_cast<const float4*>(
                    &Wt[(size_t)n * K + k0 + lk4]);
            } else {
                w = float4{0.f, 0.f, 0.f, 0.f};
            }
            Ws[lk4 + 0][r] = w.x;
            Ws[lk4 + 1][r] = w.y;
            Ws[lk4 + 2][r] = w.z;
            Ws[lk4 + 3][r] = w.w;
        }
        __syncthreads();
#pragma unroll
        for (int kk = 0; kk < 32; ++kk) {
            const float4 av = *reinterpret_cast<const float4*>(&As[kk][ty * 4]);
            const float4 wv = *reinterpret_cast<const float4*>(&Ws[kk][tx * 4]);
            const float a_[4] = {av.x, av.y, av.z, av.w};
            const float w_[4] = {wv.x, wv.y, wv.z, wv.w};
#pragma unroll
            for (int i = 0; i < 4; ++i)
#pragma unroll
                for (int j = 0; j < 4; ++j)
                    acc[i][j] += a_[i] * w_[j];
        }
        __syncthreads();
    }

#pragma unroll
    for (int i = 0; i < 4; ++i) {
        const int m = m0 + ty * 4 + i;
#pragma unroll
        for (int j = 0; j < 4; ++j) {
            const int n = n0 + tx * 4 + j;
            if (n >= N) continue;
            const float v = acc[i][j] + bias[n];
            if (MODE == 0) {
                C[(size_t)m * ldc + col_off + n] = v;
            } else {
                const int b  = m / S;
                const int s  = m - b * S;
                const int h  = n >> 5;
                const int dd = n & 31;
                C[(((size_t)(b * NH + h)) * S + s) * DH + dd] = v;
            }
        }
    }
}

// ---------------------------------------------------------------------------
// Sampling + attention-weighted aggregation.
// One 32-lane group per (b,h,q); lane = head-dim element.
// proj row layout (96 cols): [0..63] offsets (h*8 + p*2 + {x,y}),
//                            [64..95] attn logits (64 + h*4 + p)
// Output tmp[(b*Q+q)*256 + h*32 + lane].
// ---------------------------------------------------------------------------
__global__ __launch_bounds__(256) void sample_agg(
    const float* __restrict__ vflat,   // [B*NH][S][DH]
    const float* __restrict__ proj,    // [B*Q][96]
    const float* __restrict__ ref,     // [B*Q][2]
    float* __restrict__ tmp)           // [B*Q][256]
{
    const int g    = blockIdx.x * 8 + (threadIdx.x >> 5);
    const int lane = threadIdx.x & 31;
    const int q  = g % Q;
    const int bh = g / Q;        // b*NH + h
    const int b  = bh >> 3;
    const int h  = bh & 7;

    const size_t prow = (size_t)(b * Q + q) * 96;
    const float refx = ref[(size_t)(b * Q + q) * 2 + 0];
    const float refy = ref[(size_t)(b * Q + q) * 2 + 1];

    // softmax over the NP logits of this head
    float l[NP];
#pragma unroll
    for (int p = 0; p < NP; ++p) l[p] = proj[prow + 64 + h * 4 + p];
    const float mx = fmaxf(fmaxf(l[0], l[1]), fmaxf(l[2], l[3]));
    float e[NP];
    float esum = 0.f;
#pragma unroll
    for (int p = 0; p < NP; ++p) { e[p] = expf(l[p] - mx); esum += e[p]; }
    const float inv = 1.f / esum;

    const float* vbase = vflat + (size_t)bh * S * DH;

    float acc = 0.f;
#pragma unroll
    for (int p = 0; p < NP; ++p) {
        const float ox = proj[prow + h * 8 + p * 2 + 0];
        const float oy = proj[prow + h * 8 + p * 2 + 1];
        const float x = (refx + ox * (1.0f / WW)) * WW - 0.5f;
        const float y = (refy + oy * (1.0f / HH)) * HH - 0.5f;
        const float x0f = floorf(x);
        const float y0f = floorf(y);
        const float wx1 = x - x0f, wx0 = 1.f - wx1;
        const float wy1 = y - y0f, wy0 = 1.f - wy1;
        const int x0 = (int)x0f;
        const int y0 = (int)y0f;
        const bool vx0 = (x0f >= 0.f) && (x0f <= (float)(WW - 1));
        const bool vx1 = (x0f + 1.f >= 0.f) && (x0f + 1.f <= (float)(WW - 1));
        const bool vy0 = (y0f >= 0.f) && (y0f <= (float)(HH - 1));
        const bool vy1 = (y0f + 1.f >= 0.f) && (y0f + 1.f <= (float)(HH - 1));
        const int xi0 = min(max(x0, 0), WW - 1);
        const int xi1 = min(max(x0 + 1, 0), WW - 1);
        const int yi0 = min(max(y0, 0), HH - 1);
        const int yi1 = min(max(y0 + 1, 0), HH - 1);

        const float w00 = wx0 * wy0 * ((vx0 && vy0) ? 1.f : 0.f);
        const float w10 = wx1 * wy0 * ((vx1 && vy0) ? 1.f : 0.f);
        const float w01 = wx0 * wy1 * ((vx0 && vy1) ? 1.f : 0.f);
        const float w11 = wx1 * wy1 * ((vx1 && vy1) ? 1.f : 0.f);

        float sv = 0.f;
        sv += w00 * vbase[(size_t)(yi0 * WW + xi0) * DH + lane];
        sv += w10 * vbase[(size_t)(yi0 * WW + xi1) * DH + lane];
        sv += w01 * vbase[(size_t)(yi1 * WW + xi0) * DH + lane];
        sv += w11 * vbase[(size_t)(yi1 * WW + xi1) * DH + lane];

        acc += (e[p] * inv) * sv;
    }

    tmp[((size_t)(b * Q + q)) * 256 + h * 32 + lane] = acc;
}

// ---------------------------------------------------------------------------
extern "C" void kernel_launch(void* const* d_in, const int* in_sizes, int n_in,
                              void* d_out, int out_size, void* d_ws, size_t ws_size,
                              hipStream_t stream)
{
    const float* hidden = (const float*)d_in[0];   // [B,Q,256]
    const float* enc    = (const float*)d_in[1];   // [B,S,256]
    const float* refp   = (const float*)d_in[2];   // [B,Q,1,2]
    // d_in[3] = spatial_shapes (static, ignored)
    const float* W_off  = (const float*)d_in[4];   // [64,256]
    const float* b_off  = (const float*)d_in[5];   // [64]
    const float* W_attn = (const float*)d_in[6];   // [32,256]
    const float* b_attn = (const float*)d_in[7];   // [32]
    const float* W_val  = (const float*)d_in[8];   // [256,256]
    const float* b_val  = (const float*)d_in[9];   // [256]
    const float* W_out  = (const float*)d_in[10];  // [256,256]
    const float* b_out  = (const float*)d_in[11];  // [256]
    float* out = (float*)d_out;

    float* vflat = (float*)d_ws;                 // B*NH*S*DH = 10,240,000 f
    float* proj  = vflat + (size_t)B * NH * S * DH;  // B*Q*96 = 3,840,000 f
    float* tmp   = proj + (size_t)B * Q * 96;        // B*Q*256 = 10,240,000 f

    const int M = B * Q;   // 40000 (divisible by 64)

    // 1) value projection -> vflat [B*NH][S][32]
    gemm_nt<1><<<dim3(4, M / 64), 256, 0, stream>>>(
        enc, W_val, b_val, vflat, M, 256, 0, 0);

    // 2) sampling offsets (64 cols) and attention logits (32 cols) -> proj[.,96]
    gemm_nt<0><<<dim3(1, M / 64), 256, 0, stream>>>(
        hidden, W_off, b_off, proj, M, 64, 96, 0);
    gemm_nt<0><<<dim3(1, M / 64), 256, 0, stream>>>(
        hidden, W_attn, b_attn, proj, M, 32, 96, 64);

    // 3) bilinear sampling + attention-weighted sum -> tmp [B*Q][256]
    sample_agg<<<(B * NH * Q) / 8, 256, 0, stream>>>(vflat, proj, refp, tmp);

    // 4) output projection -> d_out
    gemm_nt<0><<<dim3(4, M / 64), 256, 0, stream>>>(
        tmp, W_out, b_out, out, M, 256, 256, 0);
}

// Round 2
// 156.804 us; speedup vs baseline: 1.9400x; 1.9400x over previous
//
#include <hip/hip_runtime.h>

constexpr int HH = 100;
constexpr int WW = 100;
constexpr int NH = 8;
constexpr int NP = 4;
constexpr int B  = 4;
constexpr int Q  = HH * WW;   // 10000
constexpr int S  = Q;
constexpr int K  = 256;
constexpr int DH = 32;

typedef __attribute__((ext_vector_type(8))) short short8;
typedef __attribute__((ext_vector_type(4))) float f32x4;

__device__ inline unsigned short f2bf(float f) {
    unsigned u = __builtin_bit_cast(unsigned, f);
    u += 0x7fffu + ((u >> 16) & 1u);          // round-to-nearest-even
    return (unsigned short)(u >> 16);
}
__device__ inline float bf2f(unsigned short h) {
    return __builtin_bit_cast(float, ((unsigned)h) << 16);
}

// LDS tile [64 rows][64 k] bf16, 16B-chunk XOR swizzle to kill bank conflicts.
__device__ inline void lds_store16(short* base, int row, int kcol, short8 v) {
    const int idx = row * 64 + (kcol ^ ((row & 7) << 3));
    *reinterpret_cast<short8*>(&base[idx]) = v;
}
__device__ inline short8 lds_load16(const short* base, int row, int kcol) {
    const int idx = row * 64 + (kcol ^ ((row & 7) << 3));
    return *reinterpret_cast<const short8*>(&base[idx]);
}

__device__ inline short8 cvt8(float4 a, float4 b) {
    short8 r;
    r[0] = (short)f2bf(a.x); r[1] = (short)f2bf(a.y);
    r[2] = (short)f2bf(a.z); r[3] = (short)f2bf(a.w);
    r[4] = (short)f2bf(b.x); r[5] = (short)f2bf(b.y);
    r[6] = (short)f2bf(b.z); r[7] = (short)f2bf(b.w);
    return r;
}

// ---------------------------------------------------------------------------
// bf16-MFMA GEMM: C = A[M,K] @ W[N,K]^T + bias, K=256, tile 64x64, BK=64.
// MODE 0: A f32,  out bf16 in vflat layout [B*NH][S][DH]          (value proj)
// MODE 1: A f32,  out f32  [M][96], W = {W0 rows 0..N0-1, W1 rest} (off+attn)
// MODE 2: A bf16, out f32  [M][256]                               (out proj)
// ---------------------------------------------------------------------------
template <int MODE>
__global__ __launch_bounds__(256) void gemm_mfma(
    const void* __restrict__ Ap, const float* __restrict__ W0,
    const float* __restrict__ W1, const float* __restrict__ b0,
    const float* __restrict__ b1, void* __restrict__ Cp,
    int N, int N0)
{
    __shared__ short As[64 * 64];
    __shared__ short Bs[64 * 64];

    const int tid  = threadIdx.x;
    const int m0   = blockIdx.y * 64;
    const int n0   = blockIdx.x * 64;
    const int lane = tid & 63;
    const int w    = tid >> 6;
    const int wr   = (w >> 1) * 32;
    const int wc   = (w & 1) * 32;
    const int l15  = lane & 15;
    const int l4   = lane >> 4;

    const int srow = tid >> 2;        // 0..63
    const int skq  = (tid & 3) * 16;  // 0,16,32,48

    f32x4 acc[2][2];
#pragma unroll
    for (int i = 0; i < 2; ++i)
#pragma unroll
        for (int j = 0; j < 2; ++j)
            acc[i][j] = f32x4{0.f, 0.f, 0.f, 0.f};

    for (int k0 = 0; k0 < K; k0 += 64) {
        // ---- stage A tile ----
        if constexpr (MODE == 2) {
            const unsigned short* A = (const unsigned short*)Ap;
            const unsigned short* src = &A[(size_t)(m0 + srow) * K + k0 + skq];
            short8 v0 = *reinterpret_cast<const short8*>(src);
            short8 v1 = *reinterpret_cast<const short8*>(src + 8);
            lds_store16(As, srow, skq, v0);
            lds_store16(As, srow, skq + 8, v1);
        } else {
            const float* A = (const float*)Ap;
            const float* src = &A[(size_t)(m0 + srow) * K + k0 + skq];
            float4 f0 = *reinterpret_cast<const float4*>(src);
            float4 f1 = *reinterpret_cast<const float4*>(src + 4);
            float4 f2 = *reinterpret_cast<const float4*>(src + 8);
            float4 f3 = *reinterpret_cast<const float4*>(src + 12);
            lds_store16(As, srow, skq, cvt8(f0, f1));
            lds_store16(As, srow, skq + 8, cvt8(f2, f3));
        }
        // ---- stage B (weights, always f32 in global) ----
        {
            const int n = n0 + srow;
            short8 w0v = short8{0,0,0,0,0,0,0,0};
            short8 w1v = short8{0,0,0,0,0,0,0,0};
            if (n < N) {
                const float* src = (n < N0)
                    ? &W0[(size_t)n * K + k0 + skq]
                    : &W1[(size_t)(n - N0) * K + k0 + skq];
                float4 f0 = *reinterpret_cast<const float4*>(src);
                float4 f1 = *reinterpret_cast<const float4*>(src + 4);
                float4 f2 = *reinterpret_cast<const float4*>(src + 8);
                float4 f3 = *reinterpret_cast<const float4*>(src + 12);
                w0v = cvt8(f0, f1);
                w1v = cvt8(f2, f3);
            }
            lds_store16(Bs, srow, skq, w0v);
            lds_store16(Bs, srow, skq + 8, w1v);
        }
        __syncthreads();

#pragma unroll
        for (int kk = 0; kk < 2; ++kk) {
            const int kc = kk * 32 + l4 * 8;
            short8 a0 = lds_load16(As, wr + l15, kc);
            short8 a1 = lds_load16(As, wr + 16 + l15, kc);
            short8 bb0 = lds_load16(Bs, wc + l15, kc);
            short8 bb1 = lds_load16(Bs, wc + 16 + l15, kc);
            acc[0][0] = __builtin_amdgcn_mfma_f32_16x16x32_bf16(a0, bb0, acc[0][0], 0, 0, 0);
            acc[0][1] = __builtin_amdgcn_mfma_f32_16x16x32_bf16(a0, bb1, acc[0][1], 0, 0, 0);
            acc[1][0] = __builtin_amdgcn_mfma_f32_16x16x32_bf16(a1, bb0, acc[1][0], 0, 0, 0);
            acc[1][1] = __builtin_amdgcn_mfma_f32_16x16x32_bf16(a1, bb1, acc[1][1], 0, 0, 0);
        }
        __syncthreads();
    }

    // ---- epilogue: bias + store ----
#pragma unroll
    for (int ni = 0; ni < 2; ++ni) {
        const int n = n0 + wc + ni * 16 + l15;
        if (n >= N) continue;
        const float bias = (n < N0) ? b0[n] : b1[n - N0];
#pragma unroll
        for (int mi = 0; mi < 2; ++mi) {
#pragma unroll
            for (int r = 0; r < 4; ++r) {
                const int m = m0 + wr + mi * 16 + l4 * 4 + r;
                const float v = acc[mi][ni][r] + bias;
                if constexpr (MODE == 0) {
                    const int b = m / S, s = m - (m / S) * S;
                    const int h = n >> 5, dd = n & 31;
                    ((unsigned short*)Cp)[(((size_t)(b * NH + h)) * S + s) * DH + dd] = f2bf(v);
                } else if constexpr (MODE == 1) {
                    ((float*)Cp)[(size_t)m * 96 + n] = v;
                } else {
                    ((float*)Cp)[(size_t)m * 256 + n] = v;
                }
            }
        }
    }
}

// ---------------------------------------------------------------------------
// Bilinear sampling + attention aggregation. 32-lane group per (b,h,q).
// ---------------------------------------------------------------------------
__global__ __launch_bounds__(256) void sample_agg(
    const unsigned short* __restrict__ vflat,  // [B*NH][S][DH] bf16
    const float* __restrict__ proj,            // [B*Q][96]
    const float* __restrict__ ref,             // [B*Q][2]
    unsigned short* __restrict__ tmp)          // [B*Q][256] bf16
{
    const int g    = blockIdx.x * 8 + (threadIdx.x >> 5);
    const int lane = threadIdx.x & 31;
    const int q  = g % Q;
    const int bh = g / Q;
    const int b  = bh >> 3;
    const int h  = bh & 7;

    const size_t bq   = (size_t)(b * Q + q);
    const size_t prow = bq * 96;
    const float refx = ref[bq * 2 + 0];
    const float refy = ref[bq * 2 + 1];

    float l[NP];
#pragma unroll
    for (int p = 0; p < NP; ++p) l[p] = proj[prow + 64 + h * 4 + p];
    const float mx = fmaxf(fmaxf(l[0], l[1]), fmaxf(l[2], l[3]));
    float e[NP];
    float esum = 0.f;
#pragma unroll
    for (int p = 0; p < NP; ++p) { e[p] = expf(l[p] - mx); esum += e[p]; }
    const float inv = 1.f / esum;

    const unsigned short* vbase = vflat + (size_t)bh * S * DH;

    float acc = 0.f;
#pragma unroll
    for (int p = 0; p < NP; ++p) {
        const float ox = proj[prow + h * 8 + p * 2 + 0];
        const float oy = proj[prow + h * 8 + p * 2 + 1];
        const float x = (refx + ox * (1.0f / WW)) * WW - 0.5f;
        const float y = (refy + oy * (1.0f / HH)) * HH - 0.5f;
        const float x0f = floorf(x);
        const float y0f = floorf(y);
        const float wx1 = x - x0f, wx0 = 1.f - wx1;
        const float wy1 = y - y0f, wy0 = 1.f - wy1;
        const int x0 = (int)x0f;
        const int y0 = (int)y0f;
        const bool vx0 = (x0f >= 0.f) && (x0f <= (float)(WW - 1));
        const bool vx1 = (x0f + 1.f >= 0.f) && (x0f + 1.f <= (float)(WW - 1));
        const bool vy0 = (y0f >= 0.f) && (y0f <= (float)(HH - 1));
        const bool vy1 = (y0f + 1.f >= 0.f) && (y0f + 1.f <= (float)(HH - 1));
        const int xi0 = min(max(x0, 0), WW - 1);
        const int xi1 = min(max(x0 + 1, 0), WW - 1);
        const int yi0 = min(max(y0, 0), HH - 1);
        const int yi1 = min(max(y0 + 1, 0), HH - 1);

        const float w00 = wx0 * wy0 * ((vx0 && vy0) ? 1.f : 0.f);
        const float w10 = wx1 * wy0 * ((vx1 && vy0) ? 1.f : 0.f);
        const float w01 = wx0 * wy1 * ((vx0 && vy1) ? 1.f : 0.f);
        const float w11 = wx1 * wy1 * ((vx1 && vy1) ? 1.f : 0.f);

        float sv = 0.f;
        sv += w00 * bf2f(vbase[(size_t)(yi0 * WW + xi0) * DH + lane]);
        sv += w10 * bf2f(vbase[(size_t)(yi0 * WW + xi1) * DH + lane]);
        sv += w01 * bf2f(vbase[(size_t)(yi1 * WW + xi0) * DH + lane]);
        sv += w11 * bf2f(vbase[(size_t)(yi1 * WW + xi1) * DH + lane]);

        acc += (e[p] * inv) * sv;
    }

    tmp[bq * 256 + h * 32 + lane] = f2bf(acc);
}

// ---------------------------------------------------------------------------
extern "C" void kernel_launch(void* const* d_in, const int* in_sizes, int n_in,
                              void* d_out, int out_size, void* d_ws, size_t ws_size,
                              hipStream_t stream)
{
    const float* hidden = (const float*)d_in[0];
    const float* enc    = (const float*)d_in[1];
    const float* refp   = (const float*)d_in[2];
    const float* W_off  = (const float*)d_in[4];
    const float* b_off  = (const float*)d_in[5];
    const float* W_attn = (const float*)d_in[6];
    const float* b_attn = (const float*)d_in[7];
    const float* W_val  = (const float*)d_in[8];
    const float* b_val  = (const float*)d_in[9];
    const float* W_out  = (const float*)d_in[10];
    const float* b_out  = (const float*)d_in[11];
    float* out = (float*)d_out;

    unsigned short* vflat = (unsigned short*)d_ws;                       // 10.24M bf16
    float* proj = (float*)((char*)d_ws + (size_t)B * NH * S * DH * 2);   // 3.84M f32
    unsigned short* tmp = (unsigned short*)((char*)proj + (size_t)B * Q * 96 * 4);

    const int M = B * Q;  // 40000

    // 1) value projection -> vflat bf16 [B*NH][S][32]
    gemm_mfma<0><<<dim3(4, M / 64), 256, 0, stream>>>(
        (const void*)enc, W_val, W_val, b_val, b_val, (void*)vflat, 256, 256);

    // 2) fused offsets+attn projection -> proj f32 [B*Q][96]
    gemm_mfma<1><<<dim3(2, M / 64), 256, 0, stream>>>(
        (const void*)hidden, W_off, W_attn, b_off, b_attn, (void*)proj, 96, 64);

    // 3) bilinear sampling + softmax aggregation -> tmp bf16 [B*Q][256]
    sample_agg<<<(B * NH * Q) / 8, 256, 0, stream>>>(vflat, proj, refp, tmp);

    // 4) output projection -> d_out f32
    gemm_mfma<2><<<dim3(4, M / 64), 256, 0, stream>>>(
        (const void*)tmp, W_out, W_out, b_out, b_out, (void*)out, 256, 256);
}

// Round 3
// 108.073 us; speedup vs baseline: 2.8148x; 1.4509x over previous
//
#include <hip/hip_runtime.h>

constexpr int HH = 100;
constexpr int WW = 100;
constexpr int NH = 8;
constexpr int NP = 4;
constexpr int B  = 4;
constexpr int Q  = HH * WW;   // 10000
constexpr int S  = Q;
constexpr int K  = 256;
constexpr int DH = 32;

typedef __attribute__((ext_vector_type(8))) short short8;
typedef __attribute__((ext_vector_type(4))) float f32x4;

struct ushort4_t { unsigned short x, y, z, w; };

__device__ inline unsigned short f2bf(float f) {
    unsigned u = __builtin_bit_cast(unsigned, f);
    u += 0x7fffu + ((u >> 16) & 1u);          // round-to-nearest-even
    return (unsigned short)(u >> 16);
}
__device__ inline float bf2f(unsigned short h) {
    return __builtin_bit_cast(float, ((unsigned)h) << 16);
}

// LDS tile [64 rows][64 k] bf16, 16B-chunk XOR swizzle to kill bank conflicts.
__device__ inline void lds_store16(short* base, int row, int kcol, short8 v) {
    const int idx = row * 64 + (kcol ^ ((row & 7) << 3));
    *reinterpret_cast<short8*>(&base[idx]) = v;
}
__device__ inline short8 lds_load16(const short* base, int row, int kcol) {
    const int idx = row * 64 + (kcol ^ ((row & 7) << 3));
    return *reinterpret_cast<const short8*>(&base[idx]);
}

__device__ inline short8 cvt8(float4 a, float4 b) {
    short8 r;
    r[0] = (short)f2bf(a.x); r[1] = (short)f2bf(a.y);
    r[2] = (short)f2bf(a.z); r[3] = (short)f2bf(a.w);
    r[4] = (short)f2bf(b.x); r[5] = (short)f2bf(b.y);
    r[6] = (short)f2bf(b.z); r[7] = (short)f2bf(b.w);
    return r;
}

// ---------------------------------------------------------------------------
// bf16-MFMA GEMM: C = A[M,K] @ W[N,K]^T + bias, K=256, tile 64x64, BK=64.
// MODE 0: A f32,  out bf16 in vflat layout [B*NH][S][DH]          (value proj)
// MODE 1: A f32,  out f32  [M][96], W = {W0 rows 0..N0-1, W1 rest} (off+attn)
// MODE 2: A bf16, out f32  [M][256]                               (out proj)
// ---------------------------------------------------------------------------
template <int MODE>
__global__ __launch_bounds__(256) void gemm_mfma(
    const void* __restrict__ Ap, const float* __restrict__ W0,
    const float* __restrict__ W1, const float* __restrict__ b0,
    const float* __restrict__ b1, void* __restrict__ Cp,
    int N, int N0)
{
    __shared__ short As[64 * 64];
    __shared__ short Bs[64 * 64];

    const int tid  = threadIdx.x;
    const int m0   = blockIdx.y * 64;
    const int n0   = blockIdx.x * 64;
    const int lane = tid & 63;
    const int w    = tid >> 6;
    const int wr   = (w >> 1) * 32;
    const int wc   = (w & 1) * 32;
    const int l15  = lane & 15;
    const int l4   = lane >> 4;

    const int srow = tid >> 2;        // 0..63
    const int skq  = (tid & 3) * 16;  // 0,16,32,48

    f32x4 acc[2][2];
#pragma unroll
    for (int i = 0; i < 2; ++i)
#pragma unroll
        for (int j = 0; j < 2; ++j)
            acc[i][j] = f32x4{0.f, 0.f, 0.f, 0.f};

    for (int k0 = 0; k0 < K; k0 += 64) {
        // ---- stage A tile ----
        if constexpr (MODE == 2) {
            const unsigned short* A = (const unsigned short*)Ap;
            const unsigned short* src = &A[(size_t)(m0 + srow) * K + k0 + skq];
            short8 v0 = *reinterpret_cast<const short8*>(src);
            short8 v1 = *reinterpret_cast<const short8*>(src + 8);
            lds_store16(As, srow, skq, v0);
            lds_store16(As, srow, skq + 8, v1);
        } else {
            const float* A = (const float*)Ap;
            const float* src = &A[(size_t)(m0 + srow) * K + k0 + skq];
            float4 f0 = *reinterpret_cast<const float4*>(src);
            float4 f1 = *reinterpret_cast<const float4*>(src + 4);
            float4 f2 = *reinterpret_cast<const float4*>(src + 8);
            float4 f3 = *reinterpret_cast<const float4*>(src + 12);
            lds_store16(As, srow, skq, cvt8(f0, f1));
            lds_store16(As, srow, skq + 8, cvt8(f2, f3));
        }
        // ---- stage B (weights, always f32 in global) ----
        {
            const int n = n0 + srow;
            short8 w0v = short8{0,0,0,0,0,0,0,0};
            short8 w1v = short8{0,0,0,0,0,0,0,0};
            if (n < N) {
                const float* src = (n < N0)
                    ? &W0[(size_t)n * K + k0 + skq]
                    : &W1[(size_t)(n - N0) * K + k0 + skq];
                float4 f0 = *reinterpret_cast<const float4*>(src);
                float4 f1 = *reinterpret_cast<const float4*>(src + 4);
                float4 f2 = *reinterpret_cast<const float4*>(src + 8);
                float4 f3 = *reinterpret_cast<const float4*>(src + 12);
                w0v = cvt8(f0, f1);
                w1v = cvt8(f2, f3);
            }
            lds_store16(Bs, srow, skq, w0v);
            lds_store16(Bs, srow, skq + 8, w1v);
        }
        __syncthreads();

#pragma unroll
        for (int kk = 0; kk < 2; ++kk) {
            const int kc = kk * 32 + l4 * 8;
            short8 a0 = lds_load16(As, wr + l15, kc);
            short8 a1 = lds_load16(As, wr + 16 + l15, kc);
            short8 bb0 = lds_load16(Bs, wc + l15, kc);
            short8 bb1 = lds_load16(Bs, wc + 16 + l15, kc);
            acc[0][0] = __builtin_amdgcn_mfma_f32_16x16x32_bf16(a0, bb0, acc[0][0], 0, 0, 0);
            acc[0][1] = __builtin_amdgcn_mfma_f32_16x16x32_bf16(a0, bb1, acc[0][1], 0, 0, 0);
            acc[1][0] = __builtin_amdgcn_mfma_f32_16x16x32_bf16(a1, bb0, acc[1][0], 0, 0, 0);
            acc[1][1] = __builtin_amdgcn_mfma_f32_16x16x32_bf16(a1, bb1, acc[1][1], 0, 0, 0);
        }
        __syncthreads();
    }

    // ---- epilogue: bias + store ----
#pragma unroll
    for (int ni = 0; ni < 2; ++ni) {
        const int n = n0 + wc + ni * 16 + l15;
        if (n >= N) continue;
        const float bias = (n < N0) ? b0[n] : b1[n - N0];
#pragma unroll
        for (int mi = 0; mi < 2; ++mi) {
#pragma unroll
            for (int r = 0; r < 4; ++r) {
                const int m = m0 + wr + mi * 16 + l4 * 4 + r;
                const float v = acc[mi][ni][r] + bias;
                if constexpr (MODE == 0) {
                    const int b = m / S, s = m - (m / S) * S;
                    const int h = n >> 5, dd = n & 31;
                    ((unsigned short*)Cp)[(((size_t)(b * NH + h)) * S + s) * DH + dd] = f2bf(v);
                } else if constexpr (MODE == 1) {
                    ((float*)Cp)[(size_t)m * 96 + n] = v;
                } else {
                    ((float*)Cp)[(size_t)m * 256 + n] = v;
                }
            }
        }
    }
}

// ---------------------------------------------------------------------------
// Bilinear sampling + attention aggregation.
// 8 lanes per (b,h,q) group; lane owns 4 consecutive d-elements (ushort4).
// 32 groups per 256-thread block. XCD-swizzled so each XCD sees a
// contiguous range of (b,h) slices (L2 locality for vflat).
// ---------------------------------------------------------------------------
__global__ __launch_bounds__(256) void sample_agg(
    const unsigned short* __restrict__ vflat,  // [B*NH][S][DH] bf16
    const float* __restrict__ proj,            // [B*Q][96]
    const float* __restrict__ ref,             // [B*Q][2]
    unsigned short* __restrict__ tmp)          // [B*Q][256] bf16
{
    // bijective XCD swizzle: grid = 10000 blocks, 10000 % 8 == 0
    const int nblk = gridDim.x;
    const int cpx  = nblk >> 3;                       // blocks per XCD chunk
    const int swz  = (blockIdx.x & 7) * cpx + (blockIdx.x >> 3);

    const int lg   = threadIdx.x >> 3;   // 0..31 local group
    const int lane = threadIdx.x & 7;    // 0..7
    const int d0   = lane * 4;

    const int g  = swz * 32 + lg;        // global group id, < 320000
    const int q  = g % Q;
    const int bh = g / Q;
    const int b  = bh >> 3;
    const int h  = bh & 7;

    const size_t bq   = (size_t)b * Q + q;
    const float refx = ref[bq * 2 + 0];
    const float refy = ref[bq * 2 + 1];
    const float* pr = proj + bq * 96;

    // softmax over NP logits of this head
    float l[NP];
#pragma unroll
    for (int p = 0; p < NP; ++p) l[p] = pr[64 + h * 4 + p];
    const float mx = fmaxf(fmaxf(l[0], l[1]), fmaxf(l[2], l[3]));
    float e[NP];
    float esum = 0.f;
#pragma unroll
    for (int p = 0; p < NP; ++p) { e[p] = __expf(l[p] - mx); esum += e[p]; }
    const float inv = 1.f / esum;

    const unsigned short* vbase = vflat + (size_t)bh * (S * DH);

    // compute all corner indices/weights first (lets loads issue together)
    int   cidx[NP][4];
    float cw[NP][4];
#pragma unroll
    for (int p = 0; p < NP; ++p) {
        const float ox = pr[h * 8 + p * 2 + 0];
        const float oy = pr[h * 8 + p * 2 + 1];
        const float x = (refx + ox * (1.0f / WW)) * WW - 0.5f;
        const float y = (refy + oy * (1.0f / HH)) * HH - 0.5f;
        const float x0f = floorf(x);
        const float y0f = floorf(y);
        const float wx1 = x - x0f, wx0 = 1.f - wx1;
        const float wy1 = y - y0f, wy0 = 1.f - wy1;
        const int x0 = (int)x0f;
        const int y0 = (int)y0f;
        const bool vx0 = (x0 >= 0) && (x0 <= WW - 1);
        const bool vx1 = (x0 + 1 >= 0) && (x0 + 1 <= WW - 1);
        const bool vy0 = (y0 >= 0) && (y0 <= HH - 1);
        const bool vy1 = (y0 + 1 >= 0) && (y0 + 1 <= HH - 1);
        const int xi0 = min(max(x0, 0), WW - 1);
        const int xi1 = min(max(x0 + 1, 0), WW - 1);
        const int yi0 = min(max(y0, 0), HH - 1);
        const int yi1 = min(max(y0 + 1, 0), HH - 1);
        const float ap = e[p] * inv;
        cw[p][0] = ap * wx0 * wy0 * ((vx0 && vy0) ? 1.f : 0.f);
        cw[p][1] = ap * wx1 * wy0 * ((vx1 && vy0) ? 1.f : 0.f);
        cw[p][2] = ap * wx0 * wy1 * ((vx0 && vy1) ? 1.f : 0.f);
        cw[p][3] = ap * wx1 * wy1 * ((vx1 && vy1) ? 1.f : 0.f);
        cidx[p][0] = (yi0 * WW + xi0) * DH + d0;
        cidx[p][1] = (yi0 * WW + xi1) * DH + d0;
        cidx[p][2] = (yi1 * WW + xi0) * DH + d0;
        cidx[p][3] = (yi1 * WW + xi1) * DH + d0;
    }

    float a0 = 0.f, a1 = 0.f, a2 = 0.f, a3 = 0.f;
#pragma unroll
    for (int p = 0; p < NP; ++p) {
#pragma unroll
        for (int c = 0; c < 4; ++c) {
            const ushort4_t v = *reinterpret_cast<const ushort4_t*>(&vbase[cidx[p][c]]);
            const float wgt = cw[p][c];
            a0 = fmaf(wgt, bf2f(v.x), a0);
            a1 = fmaf(wgt, bf2f(v.y), a1);
            a2 = fmaf(wgt, bf2f(v.z), a2);
            a3 = fmaf(wgt, bf2f(v.w), a3);
        }
    }

    ushort4_t o;
    o.x = f2bf(a0); o.y = f2bf(a1); o.z = f2bf(a2); o.w = f2bf(a3);
    *reinterpret_cast<ushort4_t*>(&tmp[bq * 256 + h * 32 + d0]) = o;
}

// ---------------------------------------------------------------------------
extern "C" void kernel_launch(void* const* d_in, const int* in_sizes, int n_in,
                              void* d_out, int out_size, void* d_ws, size_t ws_size,
                              hipStream_t stream)
{
    const float* hidden = (const float*)d_in[0];
    const float* enc    = (const float*)d_in[1];
    const float* refp   = (const float*)d_in[2];
    const float* W_off  = (const float*)d_in[4];
    const float* b_off  = (const float*)d_in[5];
    const float* W_attn = (const float*)d_in[6];
    const float* b_attn = (const float*)d_in[7];
    const float* W_val  = (const float*)d_in[8];
    const float* b_val  = (const float*)d_in[9];
    const float* W_out  = (const float*)d_in[10];
    const float* b_out  = (const float*)d_in[11];
    float* out = (float*)d_out;

    unsigned short* vflat = (unsigned short*)d_ws;                       // 10.24M bf16
    float* proj = (float*)((char*)d_ws + (size_t)B * NH * S * DH * 2);   // 3.84M f32
    unsigned short* tmp = (unsigned short*)((char*)proj + (size_t)B * Q * 96 * 4);

    const int M = B * Q;  // 40000

    // 1) value projection -> vflat bf16 [B*NH][S][32]
    gemm_mfma<0><<<dim3(4, M / 64), 256, 0, stream>>>(
        (const void*)enc, W_val, W_val, b_val, b_val, (void*)vflat, 256, 256);

    // 2) fused offsets+attn projection -> proj f32 [B*Q][96]
    gemm_mfma<1><<<dim3(2, M / 64), 256, 0, stream>>>(
        (const void*)hidden, W_off, W_attn, b_off, b_attn, (void*)proj, 96, 64);

    // 3) bilinear sampling + softmax aggregation -> tmp bf16 [B*Q][256]
    sample_agg<<<(B * NH * Q) / 32, 256, 0, stream>>>(vflat, proj, refp, tmp);

    // 4) output projection -> d_out f32
    gemm_mfma<2><<<dim3(4, M / 64), 256, 0, stream>>>(
        (const void*)tmp, W_out, W_out, b_out, b_out, (void*)out, 256, 256);
}

// Round 4
// 89.460 us; speedup vs baseline: 3.4004x; 1.2081x over previous
//
#include <hip/hip_runtime.h>

constexpr int HH = 100;
constexpr int WW = 100;
constexpr int NH = 8;
constexpr int NP = 4;
constexpr int B  = 4;
constexpr int Q  = HH * WW;   // 10000
constexpr int S  = Q;
constexpr int K  = 256;
constexpr int DH = 32;

typedef __attribute__((ext_vector_type(8))) short short8;
typedef __attribute__((ext_vector_type(4))) float f32x4;

struct ushort4_t { unsigned short x, y, z, w; };

__device__ inline unsigned short f2bf(float f) {
    unsigned u = __builtin_bit_cast(unsigned, f);
    u += 0x7fffu + ((u >> 16) & 1u);          // round-to-nearest-even
    return (unsigned short)(u >> 16);
}
__device__ inline float bf2f(unsigned short h) {
    return __builtin_bit_cast(float, ((unsigned)h) << 16);
}

// LDS tile [rows][64 k] bf16, 16B-chunk XOR swizzle to kill bank conflicts.
__device__ inline void lds_store16(short* base, int row, int kcol, short8 v) {
    const int idx = row * 64 + (kcol ^ ((row & 7) << 3));
    *reinterpret_cast<short8*>(&base[idx]) = v;
}
__device__ inline short8 lds_load16(const short* base, int row, int kcol) {
    const int idx = row * 64 + (kcol ^ ((row & 7) << 3));
    return *reinterpret_cast<const short8*>(&base[idx]);
}

__device__ inline short8 cvt8(float4 a, float4 b) {
    short8 r;
    r[0] = (short)f2bf(a.x); r[1] = (short)f2bf(a.y);
    r[2] = (short)f2bf(a.z); r[3] = (short)f2bf(a.w);
    r[4] = (short)f2bf(b.x); r[5] = (short)f2bf(b.y);
    r[6] = (short)f2bf(b.z); r[7] = (short)f2bf(b.w);
    return r;
}

// ---------------------------------------------------------------------------
// bf16-MFMA GEMM: C = A[M,K] @ W[N,K]^T + bias, K=256.
// Tile 64 x NT (full N per block) -> A panel read exactly once.
// 512 threads = 8 waves. MODE 0/2 (NT=256): wave owns 64x32 (4 m-frag x 2 n-frag).
// MODE 1 (NT=96): wave w<6 owns 64x16; waves 6,7 stage only.
// Register prefetch: next k-tile's global loads issue before the MFMA cluster.
// MODE 0: A f32,  out bf16 vflat layout [B*NH][S][DH]     (value proj)
// MODE 1: A f32,  out f32 [M][96], W={W0:N0 rows, W1 rest} (off+attn)
// MODE 2: A bf16, out f32 [M][256]                         (out proj)
// ---------------------------------------------------------------------------
template <int MODE, int NT>
__global__ __launch_bounds__(512) void gemm_mfma(
    const void* __restrict__ Ap, const float* __restrict__ W0,
    const float* __restrict__ W1, const float* __restrict__ b0,
    const float* __restrict__ b1, void* __restrict__ Cp, int N0)
{
    constexpr int BROWS = (NT + 63) / 64;

    __shared__ short As[64 * 64];
    __shared__ short Bs[NT * 64];

    const int tid  = threadIdx.x;
    const int m0   = blockIdx.x * 64;
    const int lane = tid & 63;
    const int w    = tid >> 6;        // 0..7
    const int l15  = lane & 15;
    const int l4   = lane >> 4;
    const int srow = tid >> 3;        // 0..63
    const int sk8  = (tid & 7) * 8;   // 0..56 step 8

    const int n_base = (MODE == 1) ? w * 16 : w * 32;
    constexpr int NF = (MODE == 1) ? 1 : 2;

    f32x4 acc[4][2];
#pragma unroll
    for (int i = 0; i < 4; ++i)
#pragma unroll
        for (int j = 0; j < 2; ++j)
            acc[i][j] = f32x4{0.f, 0.f, 0.f, 0.f};

    // prefetch registers
    float4 fa0, fa1;
    short8 sa;
    float4 fb[BROWS][2];

    auto load_tile = [&](int k0) {
        if constexpr (MODE == 2) {
            const unsigned short* A = (const unsigned short*)Ap;
            sa = *reinterpret_cast<const short8*>(&A[(size_t)(m0 + srow) * K + k0 + sk8]);
        } else {
            const float* A = (const float*)Ap;
            const float* s = &A[(size_t)(m0 + srow) * K + k0 + sk8];
            fa0 = *reinterpret_cast<const float4*>(s);
            fa1 = *reinterpret_cast<const float4*>(s + 4);
        }
#pragma unroll
        for (int i = 0; i < BROWS; ++i) {
            const int row = srow + 64 * i;
            if ((NT % 64 == 0) || row < NT) {
                const float* s = (row < N0)
                    ? &W0[(size_t)row * K + k0 + sk8]
                    : &W1[(size_t)(row - N0) * K + k0 + sk8];
                fb[i][0] = *reinterpret_cast<const float4*>(s);
                fb[i][1] = *reinterpret_cast<const float4*>(s + 4);
            }
        }
    };
    auto write_lds = [&]() {
        if constexpr (MODE == 2) {
            lds_store16(As, srow, sk8, sa);
        } else {
            lds_store16(As, srow, sk8, cvt8(fa0, fa1));
        }
#pragma unroll
        for (int i = 0; i < BROWS; ++i) {
            const int row = srow + 64 * i;
            if ((NT % 64 == 0) || row < NT)
                lds_store16(Bs, row, sk8, cvt8(fb[i][0], fb[i][1]));
        }
    };

    load_tile(0);
    for (int k0 = 0; k0 < K; k0 += 64) {
        write_lds();
        __syncthreads();
        if (k0 + 64 < K) load_tile(k0 + 64);   // overlaps MFMA below
        if (n_base < NT) {
#pragma unroll
            for (int kk = 0; kk < 2; ++kk) {
                const int kc = kk * 32 + l4 * 8;
                short8 a[4];
#pragma unroll
                for (int mf = 0; mf < 4; ++mf)
                    a[mf] = lds_load16(As, mf * 16 + l15, kc);
#pragma unroll
                for (int nf = 0; nf < NF; ++nf) {
                    const short8 bv = lds_load16(Bs, n_base + nf * 16 + l15, kc);
#pragma unroll
                    for (int mf = 0; mf < 4; ++mf)
                        acc[mf][nf] = __builtin_amdgcn_mfma_f32_16x16x32_bf16(
                            a[mf], bv, acc[mf][nf], 0, 0, 0);
                }
            }
        }
        __syncthreads();
    }

    // ---- epilogue: bias + store ----
#pragma unroll
    for (int nf = 0; nf < NF; ++nf) {
        const int n = n_base + nf * 16 + l15;
        if (n >= NT) continue;
        const float bias = (n < N0) ? b0[n] : b1[n - N0];
#pragma unroll
        for (int mf = 0; mf < 4; ++mf) {
#pragma unroll
            for (int r = 0; r < 4; ++r) {
                const int m = m0 + mf * 16 + l4 * 4 + r;
                const float v = acc[mf][nf][r] + bias;
                if constexpr (MODE == 0) {
                    const int b = m / S, s = m - (m / S) * S;
                    const int h = n >> 5, dd = n & 31;
                    ((unsigned short*)Cp)[(((size_t)(b * NH + h)) * S + s) * DH + dd] = f2bf(v);
                } else if constexpr (MODE == 1) {
                    ((float*)Cp)[(size_t)m * 96 + n] = v;
                } else {
                    ((float*)Cp)[(size_t)m * 256 + n] = v;
                }
            }
        }
    }
}

// ---------------------------------------------------------------------------
// Bilinear sampling + attention aggregation.
// 8 lanes per (b,h,q) group; lane owns 4 consecutive d-elements (ushort4).
// 32 groups per 256-thread block. XCD-swizzled so each XCD sees a
// contiguous range of (b,h) slices (L2 locality for vflat).
// ---------------------------------------------------------------------------
__global__ __launch_bounds__(256) void sample_agg(
    const unsigned short* __restrict__ vflat,  // [B*NH][S][DH] bf16
    const float* __restrict__ proj,            // [B*Q][96]
    const float* __restrict__ ref,             // [B*Q][2]
    unsigned short* __restrict__ tmp)          // [B*Q][256] bf16
{
    // bijective XCD swizzle: grid = 10000 blocks, 10000 % 8 == 0
    const int nblk = gridDim.x;
    const int cpx  = nblk >> 3;                       // blocks per XCD chunk
    const int swz  = (blockIdx.x & 7) * cpx + (blockIdx.x >> 3);

    const int lg   = threadIdx.x >> 3;   // 0..31 local group
    const int lane = threadIdx.x & 7;    // 0..7
    const int d0   = lane * 4;

    const int g  = swz * 32 + lg;        // global group id, < 320000
    const int q  = g % Q;
    const int bh = g / Q;
    const int b  = bh >> 3;
    const int h  = bh & 7;

    const size_t bq   = (size_t)b * Q + q;
    const float refx = ref[bq * 2 + 0];
    const float refy = ref[bq * 2 + 1];
    const float* pr = proj + bq * 96;

    // softmax over NP logits of this head
    float l[NP];
#pragma unroll
    for (int p = 0; p < NP; ++p) l[p] = pr[64 + h * 4 + p];
    const float mx = fmaxf(fmaxf(l[0], l[1]), fmaxf(l[2], l[3]));
    float e[NP];
    float esum = 0.f;
#pragma unroll
    for (int p = 0; p < NP; ++p) { e[p] = __expf(l[p] - mx); esum += e[p]; }
    const float inv = 1.f / esum;

    const unsigned short* vbase = vflat + (size_t)bh * (S * DH);

    // compute all corner indices/weights first (lets loads issue together)
    int   cidx[NP][4];
    float cw[NP][4];
#pragma unroll
    for (int p = 0; p < NP; ++p) {
        const float ox = pr[h * 8 + p * 2 + 0];
        const float oy = pr[h * 8 + p * 2 + 1];
        const float x = (refx + ox * (1.0f / WW)) * WW - 0.5f;
        const float y = (refy + oy * (1.0f / HH)) * HH - 0.5f;
        const float x0f = floorf(x);
        const float y0f = floorf(y);
        const float wx1 = x - x0f, wx0 = 1.f - wx1;
        const float wy1 = y - y0f, wy0 = 1.f - wy1;
        const int x0 = (int)x0f;
        const int y0 = (int)y0f;
        const bool vx0 = (x0 >= 0) && (x0 <= WW - 1);
        const bool vx1 = (x0 + 1 >= 0) && (x0 + 1 <= WW - 1);
        const bool vy0 = (y0 >= 0) && (y0 <= HH - 1);
        const bool vy1 = (y0 + 1 >= 0) && (y0 + 1 <= HH - 1);
        const int xi0 = min(max(x0, 0), WW - 1);
        const int xi1 = min(max(x0 + 1, 0), WW - 1);
        const int yi0 = min(max(y0, 0), HH - 1);
        const int yi1 = min(max(y0 + 1, 0), HH - 1);
        const float ap = e[p] * inv;
        cw[p][0] = ap * wx0 * wy0 * ((vx0 && vy0) ? 1.f : 0.f);
        cw[p][1] = ap * wx1 * wy0 * ((vx1 && vy0) ? 1.f : 0.f);
        cw[p][2] = ap * wx0 * wy1 * ((vx0 && vy1) ? 1.f : 0.f);
        cw[p][3] = ap * wx1 * wy1 * ((vx1 && vy1) ? 1.f : 0.f);
        cidx[p][0] = (yi0 * WW + xi0) * DH + d0;
        cidx[p][1] = (yi0 * WW + xi1) * DH + d0;
        cidx[p][2] = (yi1 * WW + xi0) * DH + d0;
        cidx[p][3] = (yi1 * WW + xi1) * DH + d0;
    }

    float a0 = 0.f, a1 = 0.f, a2 = 0.f, a3 = 0.f;
#pragma unroll
    for (int p = 0; p < NP; ++p) {
#pragma unroll
        for (int c = 0; c < 4; ++c) {
            const ushort4_t v = *reinterpret_cast<const ushort4_t*>(&vbase[cidx[p][c]]);
            const float wgt = cw[p][c];
            a0 = fmaf(wgt, bf2f(v.x), a0);
            a1 = fmaf(wgt, bf2f(v.y), a1);
            a2 = fmaf(wgt, bf2f(v.z), a2);
            a3 = fmaf(wgt, bf2f(v.w), a3);
        }
    }

    ushort4_t o;
    o.x = f2bf(a0); o.y = f2bf(a1); o.z = f2bf(a2); o.w = f2bf(a3);
    *reinterpret_cast<ushort4_t*>(&tmp[bq * 256 + h * 32 + d0]) = o;
}

// ---------------------------------------------------------------------------
extern "C" void kernel_launch(void* const* d_in, const int* in_sizes, int n_in,
                              void* d_out, int out_size, void* d_ws, size_t ws_size,
                              hipStream_t stream)
{
    const float* hidden = (const float*)d_in[0];
    const float* enc    = (const float*)d_in[1];
    const float* refp   = (const float*)d_in[2];
    const float* W_off  = (const float*)d_in[4];
    const float* b_off  = (const float*)d_in[5];
    const float* W_attn = (const float*)d_in[6];
    const float* b_attn = (const float*)d_in[7];
    const float* W_val  = (const float*)d_in[8];
    const float* b_val  = (const float*)d_in[9];
    const float* W_out  = (const float*)d_in[10];
    const float* b_out  = (const float*)d_in[11];
    float* out = (float*)d_out;

    unsigned short* vflat = (unsigned short*)d_ws;                       // 10.24M bf16
    float* proj = (float*)((char*)d_ws + (size_t)B * NH * S * DH * 2);   // 3.84M f32
    unsigned short* tmp = (unsigned short*)((char*)proj + (size_t)B * Q * 96 * 4);

    const int M = B * Q;  // 40000, = 625 * 64

    // 1) value projection -> vflat bf16 [B*NH][S][32]
    gemm_mfma<0, 256><<<M / 64, 512, 0, stream>>>(
        (const void*)enc, W_val, W_val, b_val, b_val, (void*)vflat, 256);

    // 2) fused offsets+attn projection -> proj f32 [B*Q][96]
    gemm_mfma<1, 96><<<M / 64, 512, 0, stream>>>(
        (const void*)hidden, W_off, W_attn, b_off, b_attn, (void*)proj, 64);

    // 3) bilinear sampling + softmax aggregation -> tmp bf16 [B*Q][256]
    sample_agg<<<(B * NH * Q) / 32, 256, 0, stream>>>(vflat, proj, refp, tmp);

    // 4) output projection -> d_out f32
    gemm_mfma<2, 256><<<M / 64, 512, 0, stream>>>(
        (const void*)tmp, W_out, W_out, b_out, b_out, (void*)out, 256);
}